// Round 5
// baseline (399.258 us; speedup 1.0000x reference)
//
#include <hip/hip_runtime.h>
#include <hip/hip_bf16.h>

// Problem constants
#define B_   64
#define L_   1024
#define H_   512
#define T_   100
#define C_   97
#define TP_  112   // T padded to 7*16

typedef _Float16 h8 __attribute__((ext_vector_type(8)));   // 8 fp16 (4 VGPRs)
typedef __attribute__((ext_vector_type(4))) float f32x4;   // MFMA C/D

// ---------------------------------------------------------------------------
// k0: prep. pos_emb fp32 -> fp16 [112][512] (rows 100..111 zero);
//     W_gen fp32 -> fp16 [112][512] (rows 97..111 zero). Grid 224.
// ---------------------------------------------------------------------------
__global__ __launch_bounds__(256) void k0_prep(
    const float* __restrict__ emb, const float* __restrict__ W,
    _Float16* __restrict__ embh, _Float16* __restrict__ Wh) {
  const int row = blockIdx.x, tid = threadIdx.x;
  if (row < TP_) {
    for (int j = tid; j < H_; j += 256)
      embh[(size_t)row * H_ + j] =
          (row < T_) ? (_Float16)emb[(size_t)row * H_ + j] : (_Float16)0.f;
  } else {
    const int c = row - TP_;
    for (int j = tid; j < H_; j += 256)
      Wh[(size_t)c * H_ + j] =
          (c < C_) ? (_Float16)W[(size_t)c * H_ + j] : (_Float16)0.f;
  }
}

// ---------------------------------------------------------------------------
// K1: scores = fmap @ emb^T (f16 MFMA). Grid 512, block 512 (8 waves x 16
// rows = 128 rows/block) -> 2 blocks/CU, 16 waves/CU for latency hiding.
// Stores sc[l][t] = fp16(s - M_blk) (natural layout; K2 transposes) and
// per-128-row-block stats part[bid][t] = (M, S).
// ---------------------------------------------------------------------------
__global__ __launch_bounds__(512, 4) void k1_scores(
    const float* __restrict__ fmap, const _Float16* __restrict__ embh,
    _Float16* __restrict__ sc, float* __restrict__ part) {
  __shared__ float red_m[8 * TP_];
  __shared__ float red_s[8 * TP_];
  __shared__ float sMb[TP_];
  const int tid = threadIdx.x;
  const int wave = tid >> 6, lane = tid & 63;
  const int quad = lane >> 4, cc = lane & 15;
  const int m0 = blockIdx.x * 128 + wave * 16;

  f32x4 acc[7];
#pragma unroll
  for (int i = 0; i < 7; ++i) acc[i] = (f32x4){0.f, 0.f, 0.f, 0.f};

  const float* ap = fmap + (size_t)(m0 + cc) * H_ + quad * 8;
#pragma unroll 4
  for (int k = 0; k < H_; k += 32) {
    float4 x0 = *(const float4*)(ap + k);
    float4 x1 = *(const float4*)(ap + k + 4);
    h8 a;
    a[0] = (_Float16)x0.x; a[1] = (_Float16)x0.y;
    a[2] = (_Float16)x0.z; a[3] = (_Float16)x0.w;
    a[4] = (_Float16)x1.x; a[5] = (_Float16)x1.y;
    a[6] = (_Float16)x1.z; a[7] = (_Float16)x1.w;
#pragma unroll
    for (int i = 0; i < 7; ++i) {
      h8 bf = *(const h8*)(embh + (size_t)(i * 16 + cc) * H_ + k + quad * 8);
      acc[i] = __builtin_amdgcn_mfma_f32_16x16x32_f16(a, bf, acc[i], 0, 0, 0);
    }
  }

  // per-t partial stats over this wave's 16 rows
  float pm[7], ps[7];
#pragma unroll
  for (int i = 0; i < 7; ++i) {
    float m = acc[i][0];
#pragma unroll
    for (int r = 1; r < 4; ++r) m = fmaxf(m, acc[i][r]);
    float s = 0.f;
#pragma unroll
    for (int r = 0; r < 4; ++r) s += __expf(acc[i][r] - m);
    pm[i] = m; ps[i] = s;
  }
#pragma unroll
  for (int d = 16; d < 64; d <<= 1) {     // reduce across quads (same t col)
#pragma unroll
    for (int i = 0; i < 7; ++i) {
      float om = __shfl_xor(pm[i], d, 64);
      float os = __shfl_xor(ps[i], d, 64);
      float M = fmaxf(pm[i], om);
      ps[i] = ps[i] * __expf(pm[i] - M) + os * __expf(om - M);
      pm[i] = M;
    }
  }
  if (lane < 16) {
#pragma unroll
    for (int i = 0; i < 7; ++i) {
      red_m[wave * TP_ + i * 16 + lane] = pm[i];
      red_s[wave * TP_ + i * 16 + lane] = ps[i];
    }
  }
  __syncthreads();
  if (tid < TP_) {
    float M = red_m[tid], S = red_s[tid];
#pragma unroll
    for (int w = 1; w < 8; ++w) {
      float om = red_m[w * TP_ + tid], os = red_s[w * TP_ + tid];
      float nM = fmaxf(M, om);
      S = S * __expf(M - nM) + os * __expf(om - nM);
      M = nM;
    }
    float* p = part + ((size_t)blockIdx.x * TP_ + tid) * 2;
    p[0] = M; p[1] = S;
    sMb[tid] = M;
  }
  __syncthreads();
#pragma unroll
  for (int i = 0; i < 7; ++i) {
    float mb = sMb[i * 16 + cc];
#pragma unroll
    for (int r = 0; r < 4; ++r)
      sc[(size_t)(m0 + quad * 4 + r) * TP_ + i * 16 + cc] =
          (_Float16)(acc[i][r] - mb);
  }
}

// ---------------------------------------------------------------------------
// K2: merge 8 per-chunk stats -> softmax -> LDS transpose -> attnT[b][t][l].
// Grid 512 (= B x 8 chunks of 128 l), block 256. LDS demand is ~30x below
// global traffic here, so moderate bank conflicts are irrelevant.
// ---------------------------------------------------------------------------
__global__ __launch_bounds__(256) void k2_softmax(
    const _Float16* __restrict__ sc, const float* __restrict__ part,
    _Float16* __restrict__ attnT) {
  __shared__ float sAdj[TP_], sInv[TP_];
  __shared__ _Float16 tile[TP_ * 152];   // [t][l_local], stride 152 (16B-align)
  const int b = blockIdx.x >> 3, ch = blockIdx.x & 7;
  const int tid = threadIdx.x;
  if (tid < TP_) {
    float M = -1e30f, S = 0.f;
    for (int k = 0; k < 8; ++k) {
      const float* p = part + ((size_t)(b * 8 + k) * TP_ + tid) * 2;
      float om = p[0], os = p[1];
      float nM = fmaxf(M, om);
      S = S * __expf(M - nM) + os * __expf(om - nM);
      M = nM;
    }
    sInv[tid] = 1.f / S;
    sAdj[tid] = part[((size_t)(b * 8 + ch) * TP_ + tid) * 2] - M;
  }
  __syncthreads();
  // stage 1: read sc rows coalesced, exp, write transposed into LDS
  const _Float16* sp = sc + ((size_t)(b * 8 + ch) * 128) * TP_;
#pragma unroll
  for (int j = 0; j < 7; ++j) {
    const int id = tid + j * 256;        // 1792 = 128 l x 14 t-chunks
    const int l = id / 14, tc = id % 14;
    h8 v = *(const h8*)(sp + (size_t)l * TP_ + tc * 8);
#pragma unroll
    for (int jj = 0; jj < 8; ++jj) {
      const int t = tc * 8 + jj;
      tile[t * 152 + l] = (_Float16)(__expf((float)v[jj] + sAdj[t]) * sInv[t]);
    }
  }
  __syncthreads();
  // stage 2: stream out t-rows coalesced
  _Float16* dst = attnT + (size_t)b * TP_ * L_ + ch * 128;
#pragma unroll
  for (int j = 0; j < 7; ++j) {
    const int id = tid + j * 256;        // 1792 = 112 t x 16 l-chunks
    const int t = id >> 4, c = id & 15;
    *(h8*)(dst + (size_t)t * L_ + c * 8) = *(const h8*)&tile[t * 152 + c * 8];
  }
}

// ---------------------------------------------------------------------------
// K3: ctxp[ks][b][t][h] = sum_{l in ks-chunk} attnT[b][t][l] * origin[b][l][h]
// fp16 partials. k-split x4 for occupancy: grid 2048 (hb fastest -> the 8
// h-slices of the same rows run on 8 XCDs concurrently), block 256,
// launch_bounds caps VGPR so 4 blocks/CU = 16 waves/CU are resident.
// ---------------------------------------------------------------------------
__global__ __launch_bounds__(256, 4) void k3_context(
    const _Float16* __restrict__ attnT, const float* __restrict__ origin,
    _Float16* __restrict__ ctxp) {
  const int bid = blockIdx.x;
  const int hb = (bid & 7) * 64;
  const int ks = (bid >> 3) & 3;
  const int b  = bid >> 5;
  const int tid = threadIdx.x;
  const int wave = tid >> 6, lane = tid & 63;
  const int quad = lane >> 4, cc = lane & 15;

  f32x4 acc[7];
#pragma unroll
  for (int i = 0; i < 7; ++i) acc[i] = (f32x4){0.f, 0.f, 0.f, 0.f};

  const _Float16* aA = attnT + ((size_t)b * TP_ + cc) * L_ + ks * 256 + quad * 8;
  const float* bp = origin + ((size_t)b * L_ + ks * 256 + quad * 8) * H_ +
                    hb + wave * 16 + cc;

#pragma unroll 2
  for (int l0 = 0; l0 < 256; l0 += 32) {
    h8 bfh;
#pragma unroll
    for (int j = 0; j < 8; ++j) bfh[j] = (_Float16)bp[(size_t)(l0 + j) * H_];
#pragma unroll
    for (int i = 0; i < 7; ++i) {
      h8 af = *(const h8*)(aA + (size_t)(i * 16) * L_ + l0);
      acc[i] = __builtin_amdgcn_mfma_f32_16x16x32_f16(af, bfh, acc[i], 0, 0, 0);
    }
  }
  const int h = hb + wave * 16 + cc;
  _Float16* out = ctxp + ((size_t)(ks * B_ + b) * TP_) * H_;
#pragma unroll
  for (int i = 0; i < 7; ++i)
#pragma unroll
    for (int r = 0; r < 4; ++r)
      out[(size_t)(i * 16 + quad * 4 + r) * H_ + h] = (_Float16)acc[i][r];
}

// ---------------------------------------------------------------------------
// K4: out[b,t,c] = sum_h (sum_ks ctxp[ks][b][t][h]) * W[c][h] + bias[c]
// All operands k-contiguous fp16 h8 loads; partials summed with packed adds.
// Grid 448 (= B x 7 t-tiles), block 256. Wave w covers c-tiles {w, w+4}.
// ---------------------------------------------------------------------------
__global__ __launch_bounds__(256) void k4_out(
    const _Float16* __restrict__ ctxp, const _Float16* __restrict__ Wh,
    const float* __restrict__ bias, float* __restrict__ out) {
  const int b = blockIdx.x / 7, mt = blockIdx.x % 7;
  const int tid = threadIdx.x;
  const int wave = tid >> 6, lane = tid & 63;
  const int quad = lane >> 4, cc = lane & 15;
  f32x4 acc0 = (f32x4){0.f, 0.f, 0.f, 0.f};
  f32x4 acc1 = (f32x4){0.f, 0.f, 0.f, 0.f};
  const int c0 = wave * 16 + cc;
  const int c1 = (wave + 4) * 16 + cc;          // <= 111 when hasB
  const bool hasB = (wave < 3);
  const size_t arow = ((size_t)b * TP_ + mt * 16 + cc) * H_ + quad * 8;
  const _Float16* ap0 = ctxp + arow;
  const _Float16* ap1 = ctxp + (size_t)1 * B_ * TP_ * H_ + arow;
  const _Float16* ap2 = ctxp + (size_t)2 * B_ * TP_ * H_ + arow;
  const _Float16* ap3 = ctxp + (size_t)3 * B_ * TP_ * H_ + arow;
  const _Float16* b0p = Wh + (size_t)c0 * H_ + quad * 8;
  const _Float16* b1p = Wh + (size_t)(hasB ? c1 : c0) * H_ + quad * 8;
#pragma unroll 2
  for (int k = 0; k < H_; k += 32) {
    h8 a0 = *(const h8*)(ap0 + k);
    h8 a1 = *(const h8*)(ap1 + k);
    h8 a2 = *(const h8*)(ap2 + k);
    h8 a3 = *(const h8*)(ap3 + k);
    h8 af = (a0 + a1) + (a2 + a3);
    h8 bf0 = *(const h8*)(b0p + k);
    acc0 = __builtin_amdgcn_mfma_f32_16x16x32_f16(af, bf0, acc0, 0, 0, 0);
    if (hasB) {
      h8 bf1 = *(const h8*)(b1p + k);
      acc1 = __builtin_amdgcn_mfma_f32_16x16x32_f16(af, bf1, acc1, 0, 0, 0);
    }
  }
  const float bias0 = (c0 < C_) ? bias[c0] : 0.f;
  const float bias1 = (hasB && c1 < C_) ? bias[c1] : 0.f;
#pragma unroll
  for (int r = 0; r < 4; ++r) {
    const int t = mt * 16 + quad * 4 + r;
    if (t < T_) {
      if (c0 < C_) out[((size_t)b * T_ + t) * C_ + c0] = acc0[r] + bias0;
      if (hasB && c1 < C_) out[((size_t)b * T_ + t) * C_ + c1] = acc1[r] + bias1;
    }
  }
}

// ---------------------------------------------------------------------------
extern "C" void kernel_launch(void* const* d_in, const int* in_sizes, int n_in,
                              void* d_out, int out_size, void* d_ws, size_t ws_size,
                              hipStream_t stream) {
  const float* fmap   = (const float*)d_in[0];  // [B,L,H] fp32
  const float* origin = (const float*)d_in[1];  // [B,L,H] fp32
  const float* emb    = (const float*)d_in[2];  // [T,H]   fp32
  const float* W      = (const float*)d_in[3];  // [C,H]   fp32
  const float* bias   = (const float*)d_in[4];  // [C]     fp32
  float* out = (float*)d_out;                   // [B,T,C] fp32

  char* ws = (char*)d_ws;
  // embh  f16 [112][512]          :    114,688 B @ 0
  // Wh    f16 [112][512]          :    114,688 B @ 114,688
  // sc    f16 [65536][112]        : 14,680,064 B @ 229,376
  // part  f32 [512][112][2]       :    458,752 B @ 14,909,440
  // attnT f16 [64][112][1024]     : 14,680,064 B @ 15,368,192
  // ctxp  f16 [4][64][112][512]   : 29,360,128 B @ 30,048,256  (end 59.4 MB)
  _Float16* embh  = (_Float16*)(ws);
  _Float16* Wh    = (_Float16*)(ws + 114688);
  _Float16* sc    = (_Float16*)(ws + 229376);
  float*    part  = (float*)   (ws + 14909440);
  _Float16* attnT = (_Float16*)(ws + 15368192);
  _Float16* ctxp  = (_Float16*)(ws + 30048256);

  hipLaunchKernelGGL(k0_prep,    dim3(224),  dim3(256), 0, stream, emb, W, embh, Wh);
  hipLaunchKernelGGL(k1_scores,  dim3(512),  dim3(512), 0, stream, fmap, embh, sc, part);
  hipLaunchKernelGGL(k2_softmax, dim3(512),  dim3(256), 0, stream, sc, part, attnT);
  hipLaunchKernelGGL(k3_context, dim3(2048), dim3(256), 0, stream, attnT, origin, ctxp);
  hipLaunchKernelGGL(k4_out,     dim3(448),  dim3(256), 0, stream, ctxp, Wh, bias, out);
}